// Round 3
// baseline (6479.189 us; speedup 1.0000x reference)
//
#include <hip/hip_runtime.h>

#define B_ 64
#define T_ 1024
#define I_ 16
#define H_ 512
#define O_ 3
#define NIN_ 103
#define NEX_ 409

#define NQ 4    // j-slices = blocks per batch cluster
#define JS 128  // j per slice
#define NS 8    // k-slices inside a block
#define REC_F 136
#define WT_WORDS (NQ * JS * 256)          // 131072 packed bf16x2 words
#define WT_BYTES (WT_WORDS * 4)           // 524288
#define REC_BYTES (B_ * 2 * NQ * REC_F * 4)  // 278528
#define FLAGS_OFF (WT_BYTES + REC_BYTES)
#define WS_NEED (FLAGS_OFF + B_ * NQ * 4)

__device__ __forceinline__ unsigned short f2bf(float f) {
  unsigned u = __float_as_uint(f);
  return (unsigned short)((u + 0x7fffu + ((u >> 16) & 1u)) >> 16);
}

// Pack W_h2h rows into bf16x2 words: WTp[q][j][p] = bf16(W[q*128+j][2p]) | bf16(W[..][2p+1])<<16
__global__ __launch_bounds__(256) void pack_w(const float* __restrict__ W,
                                              unsigned* __restrict__ WTp) {
  const int w = blockIdx.x * 256 + threadIdx.x;  // 131072 total
  const int q = w >> 15, j = (w >> 8) & (JS - 1), p = w & 255;
  const int jg = q * JS + j;
  const float a = W[jg * H_ + 2 * p];
  const float b = W[jg * H_ + 2 * p + 1];
  WTp[w] = (unsigned)f2bf(a) | ((unsigned)f2bf(b) << 16);
}

// ---------------------------------------------------------------------------
// 4-block-per-batch cluster RNN. Block (b,q) owns output rows [q*128,q*128+128)
// of W_h2h, LDS-resident as bf16 pairs. Per step: flag sync (>= wait, flags
// zeroed by stream-ordered memset each call), h exchange via d_ws records
// (agent-scope atomics, depth-2 parity buffers), dense LDS GEMV.
// 256 blocks x 134KB LDS x 16 waves = exactly 1 block/CU -> all co-resident
// with a REGULAR launch (no cooperative needed).
// ---------------------------------------------------------------------------
__global__ __launch_bounds__(1024, 1) void rnn4(
    const float* __restrict__ x, const float* __restrict__ noise,
    const float* __restrict__ W_i2h, const float* __restrict__ b_i2h,
    const float* __restrict__ b_h2h, const float* __restrict__ W_h2o,
    const float* __restrict__ b_h2o, const int* __restrict__ taup,
    const int* __restrict__ dtp, const unsigned* __restrict__ WTp,
    float* __restrict__ recs, int* __restrict__ flags,
    float* __restrict__ out_net, float* __restrict__ out_rnn) {
  __shared__ unsigned wt_s[WT_WORDS / NQ];  // 128 KB, XOR-16B swizzled rows
  __align__(16) __shared__ float h_s[H_];
  __align__(16) __shared__ float partial_s[NS * JS];
  __shared__ float x_s[I_];
  __shared__ float tails_in[18];
  __shared__ float tail_own[2][2][3];

  const int tid = threadIdx.x;
  const int g = blockIdx.x;
  const int b = (g >> 5) * 8 + (g & 7);  // cluster's 4 blocks share g%8 (XCD)
  const int q = (g >> 3) & 3;

  const float alpha = (float)dtp[0] / (float)taup[0];
  const float nzscale = (float)(sqrt(2.0 * (double)alpha) * 0.01);

  // ---- setup ----
  char* wt_c = (char*)wt_s;
  {
    const uint4* gsrc = (const uint4*)WTp + q * 8192;
    for (int idx = tid; idx < 8192; idx += 1024) {
      const int j = idx >> 6, cw = idx & 63;
      *(uint4*)(wt_c + j * 1024 + ((cw * 16) ^ ((j & 7) << 4))) = gsrc[idx];
    }
  }
  float wi[I_], cb = 0.f, w30 = 0.f, w31 = 0.f, w32 = 0.f, bo = 0.f;
  if (tid < JS) {
    const int jg = q * JS + tid;
#pragma unroll
    for (int i = 0; i < I_; ++i) wi[i] = W_i2h[jg * I_ + i];
    cb = b_i2h[jg] + b_h2h[jg];
    if (jg >= NIN_) {
      const int e = jg - NIN_;
      w30 = W_h2o[e];
      w31 = W_h2o[NEX_ + e];
      w32 = W_h2o[2 * NEX_ + e];
    }
  }
  if (tid >= JS && tid < JS + O_) bo = b_h2o[tid - JS];
  if (tid < H_) h_s[tid] = 0.f;
  if (tid < JS) out_rnn[(size_t)b * (T_ + 1) * H_ + q * JS + tid] = 0.f;
  if (q == 0 && tid >= JS && tid < JS + O_)
    out_net[(size_t)b * (T_ + 1) * O_ + (tid - JS)] = 0.f;
  __syncthreads();

  const int s = tid >> 7;       // k-slice 0..7
  const int j = tid & (JS - 1); // output within slice
  const int sw = (j & 7) << 4;
  const int rowbase = j * 1024;
  const int fb = b * NQ;

  for (int t = 0; t < T_; ++t) {
    // ---- prologue: sync (monotone >= wait) + stage h(t) + per-step loads ---
    if (t > 0) {
      if (tid < NQ) {
        while (__hip_atomic_load(&flags[fb + tid], __ATOMIC_ACQUIRE,
                                 __HIP_MEMORY_SCOPE_AGENT) < t)
          __builtin_amdgcn_s_sleep(1);
      }
      __syncthreads();
    }
    float nz = 0.f;
    if (tid < JS) nz = noise[((size_t)b * T_ + t) * H_ + q * JS + tid];
    if (t > 0 && tid < 3 * JS) {
      const int so = tid >> 7;
      const int qs = so + (so >= q ? 1 : 0);
      const int e = tid & (JS - 1);
      const float* r = recs + ((size_t)(b * 2 + (t & 1)) * NQ + qs) * REC_F;
      h_s[qs * JS + e] = __hip_atomic_load(r + e, __ATOMIC_RELAXED,
                                           __HIP_MEMORY_SCOPE_AGENT);
    }
    if (q == 0 && t > 0 && tid >= 384 && tid < 402) {
      const int i = tid - 384, r3 = i / 6, c = i % 6;
      const float* r = recs + ((size_t)(b * 2 + (t & 1)) * NQ + (r3 + 1)) * REC_F;
      tails_in[i] = __hip_atomic_load(r + JS + c, __ATOMIC_RELAXED,
                                      __HIP_MEMORY_SCOPE_AGENT);
    }
    if (tid < I_) x_s[tid] = x[((size_t)b * T_ + t) * I_ + tid];
    __syncthreads();  // A: h_s/x_s staged

    // ---- dense GEMV from LDS (bf16 W, fp32 h; h reads are wave-uniform
    //      broadcasts, w reads are swizzled b128) ----
    float acc = 0.f;
#pragma unroll
    for (int u = 0; u < 8; ++u) {
      const int off = s * 128 + u * 16;
      const uint4 w4 = *(const uint4*)(wt_c + rowbase + (off ^ sw));
      const float4 hA = *(const float4*)&h_s[s * 64 + u * 8];
      const float4 hB = *(const float4*)&h_s[s * 64 + u * 8 + 4];
      acc += __uint_as_float(w4.x << 16) * hA.x;
      acc += __uint_as_float(w4.x & 0xffff0000u) * hA.y;
      acc += __uint_as_float(w4.y << 16) * hA.z;
      acc += __uint_as_float(w4.y & 0xffff0000u) * hA.w;
      acc += __uint_as_float(w4.z << 16) * hB.x;
      acc += __uint_as_float(w4.z & 0xffff0000u) * hB.y;
      acc += __uint_as_float(w4.w << 16) * hB.z;
      acc += __uint_as_float(w4.w & 0xffff0000u) * hB.w;
    }
    partial_s[s * JS + j] = acc;
    __syncthreads();  // B: partials ready

    // ---- epilogue ----
    if (tid < JS) {
      const int jg = q * JS + tid;
      float sum = 0.f;
#pragma unroll
      for (int s2 = 0; s2 < NS; ++s2) sum += partial_s[s2 * JS + tid];
      float xi = 0.f;
#pragma unroll
      for (int i = 0; i < I_; ++i) xi += wi[i] * x_s[i];
      const float pre = alpha * (sum + xi + cb) + nzscale * nz;
      const float h = fmaxf(pre, 0.f);
      out_rnn[((size_t)b * (T_ + 1) + (t + 1)) * H_ + jg] = h;
      h_s[jg] = h;  // own slice for next GEMV
      float* r = recs + ((size_t)(b * 2 + ((t + 1) & 1)) * NQ + q) * REC_F;
      __hip_atomic_store(r + tid, h, __ATOMIC_RELAXED, __HIP_MEMORY_SCOPE_AGENT);
      float p0 = (jg >= NIN_) ? h * w30 : 0.f;
      float p1 = (jg >= NIN_) ? h * w31 : 0.f;
      float p2 = (jg >= NIN_) ? h * w32 : 0.f;
#pragma unroll
      for (int off = 32; off >= 1; off >>= 1) {
        p0 += __shfl_xor(p0, off, 64);
        p1 += __shfl_xor(p1, off, 64);
        p2 += __shfl_xor(p2, off, 64);
      }
      const int wv = tid >> 6;
      if ((tid & 63) == 0) {
        __hip_atomic_store(r + JS + wv * 3 + 0, p0, __ATOMIC_RELAXED, __HIP_MEMORY_SCOPE_AGENT);
        __hip_atomic_store(r + JS + wv * 3 + 1, p1, __ATOMIC_RELAXED, __HIP_MEMORY_SCOPE_AGENT);
        __hip_atomic_store(r + JS + wv * 3 + 2, p2, __ATOMIC_RELAXED, __HIP_MEMORY_SCOPE_AGENT);
        tail_own[(t + 1) & 1][wv][0] = p0;
        tail_own[(t + 1) & 1][wv][1] = p1;
        tail_own[(t + 1) & 1][wv][2] = p2;
      }
    }
    if (q == 0 && t > 0 && tid >= JS && tid < JS + O_) {
      const int o = tid - JS;
      float v = bo;
#pragma unroll
      for (int r3 = 0; r3 < 3; ++r3)
#pragma unroll
        for (int w = 0; w < 2; ++w) v += tails_in[r3 * 6 + w * 3 + o];
      v += tail_own[t & 1][0][o] + tail_own[t & 1][1][o];
      out_net[((size_t)b * (T_ + 1) + t) * O_ + o] = v;
    }
    __syncthreads();  // C: all record stores drained (vmcnt0 before barrier)
    if (tid == 0)
      __hip_atomic_store(&flags[fb + q], t + 1, __ATOMIC_RELEASE,
                         __HIP_MEMORY_SCOPE_AGENT);
  }

  // final out_net[b][T] from records(T) (parity T&1 == 0)
  if (q == 0) {
    if (tid < NQ) {
      while (__hip_atomic_load(&flags[fb + tid], __ATOMIC_ACQUIRE,
                               __HIP_MEMORY_SCOPE_AGENT) < T_)
        __builtin_amdgcn_s_sleep(1);
    }
    __syncthreads();
    if (tid >= 384 && tid < 402) {
      const int i = tid - 384, r3 = i / 6, c = i % 6;
      const float* r = recs + ((size_t)(b * 2 + 0) * NQ + (r3 + 1)) * REC_F;
      tails_in[i] = __hip_atomic_load(r + JS + c, __ATOMIC_RELAXED,
                                      __HIP_MEMORY_SCOPE_AGENT);
    }
    __syncthreads();
    if (tid >= JS && tid < JS + O_) {
      const int o = tid - JS;
      float v = bo;
#pragma unroll
      for (int r3 = 0; r3 < 3; ++r3)
#pragma unroll
        for (int w = 0; w < 2; ++w) v += tails_in[r3 * 6 + w * 3 + o];
      v += tail_own[0][0][o] + tail_own[0][1][o];
      out_net[((size_t)b * (T_ + 1) + T_) * O_ + o] = v;
    }
  }
}

// ---------------------------------------------------------------------------
// Fallback (ws too small): single-block-per-batch kernel with sparse
// outer-product from strided W. Slow but correct, needs no workspace.
// ---------------------------------------------------------------------------
__global__ __launch_bounds__(1024, 1) void rnn_fallback(
    const float* __restrict__ x, const float* __restrict__ noise,
    const float* __restrict__ W_i2h, const float* __restrict__ b_i2h,
    const float* __restrict__ Wh, const float* __restrict__ b_h2h,
    const float* __restrict__ W_h2o, const float* __restrict__ b_h2o,
    const int* __restrict__ taup, const int* __restrict__ dtp,
    float* __restrict__ out_net, float* __restrict__ out_rnn) {
  __shared__ float2 pair_s[544];
  __shared__ float cb_s[H_];
  __shared__ float w3_s[3 * 416];
  __shared__ float wpart_s[8][3];
  __shared__ int wcnt_s[8];
  __shared__ float x_s[I_];
  __shared__ int cntp_s;
  __align__(16) __shared__ float partial_s[8 * H_];

  const int tid = threadIdx.x;
  const int b = blockIdx.x;
  const int lane = tid & 63;
  const int wave = tid >> 6;
  const int slice = tid >> 7;
  const int j4 = (tid & 127) * 4;

  const float alpha = (float)dtp[0] / (float)taup[0];
  const float nzscale = (float)(sqrt(2.0 * (double)alpha) * 0.01);

  float wi[I_];
  if (tid < H_) {
#pragma unroll
    for (int i = 0; i < I_; ++i) wi[i] = W_i2h[tid * I_ + i];
    cb_s[tid] = b_i2h[tid] + b_h2h[tid];
  }
  for (int idx = tid; idx < O_ * NEX_; idx += 1024) {
    int o = idx / NEX_, e = idx - o * NEX_;
    w3_s[o * 416 + e] = W_h2o[idx];
  }
  const float myb = (tid < O_) ? b_h2o[tid] : 0.f;
  if (tid == 0) cntp_s = 0;
  float* rnn_b = out_rnn + (size_t)b * (T_ + 1) * H_;
  float* net_b = out_net + (size_t)b * (T_ + 1) * O_;
  if (tid < H_) rnn_b[tid] = 0.f;
  if (tid < O_) net_b[tid] = 0.f;
  __syncthreads();

  int cntp = 0;
  for (int t = 0; t < T_; ++t) {
    float nzv = 0.f, xv = 0.f;
    if (tid < H_) nzv = noise[((size_t)b * T_ + t) * H_ + tid];
    if (tid < I_) xv = x[((size_t)b * T_ + t) * I_ + tid];
    float4 acc = {0.f, 0.f, 0.f, 0.f};
    const int iters = cntp >> 3;
    for (int r = 0; r < iters; r += 4) {
#pragma unroll
      for (int u = 0; u < 4; ++u) {
        const float2 p = pair_s[(r + u) * 8 + slice];
        const int k = __float_as_int(p.y);
        acc.x += p.x * Wh[(size_t)(j4 + 0) * H_ + k];
        acc.y += p.x * Wh[(size_t)(j4 + 1) * H_ + k];
        acc.z += p.x * Wh[(size_t)(j4 + 2) * H_ + k];
        acc.w += p.x * Wh[(size_t)(j4 + 3) * H_ + k];
      }
    }
    if (tid < I_) x_s[tid] = xv;
    *reinterpret_cast<float4*>(partial_s + slice * H_ + j4) = acc;
    __syncthreads();
    unsigned long long mask = 0ull;
    float h = 0.f;
    if (tid < H_) {
      float sum = 0.f;
#pragma unroll
      for (int s2 = 0; s2 < 8; ++s2) sum += partial_s[s2 * H_ + tid];
      float xi = 0.f;
#pragma unroll
      for (int i = 0; i < I_; ++i) xi += wi[i] * x_s[i];
      const float pre = alpha * (sum + xi + cb_s[tid]) + nzscale * nzv;
      h = fmaxf(pre, 0.f);
      rnn_b[(size_t)(t + 1) * H_ + tid] = h;
      float p0 = 0.f, p1 = 0.f, p2 = 0.f;
      if (tid >= NIN_) {
        const int e = tid - NIN_;
        p0 = h * w3_s[e];
        p1 = h * w3_s[416 + e];
        p2 = h * w3_s[832 + e];
      }
#pragma unroll
      for (int off = 32; off >= 1; off >>= 1) {
        p0 += __shfl_xor(p0, off, 64);
        p1 += __shfl_xor(p1, off, 64);
        p2 += __shfl_xor(p2, off, 64);
      }
      mask = __ballot(h > 0.f);
      if (lane == 0) {
        wcnt_s[wave] = (int)__popcll(mask);
        wpart_s[wave][0] = p0;
        wpart_s[wave][1] = p1;
        wpart_s[wave][2] = p2;
      }
    }
    __syncthreads();
    if (tid < H_) {
      int base = 0, cnt = 0;
#pragma unroll
      for (int w = 0; w < 8; ++w) {
        const int c = wcnt_s[w];
        if (w < wave) base += c;
        cnt += c;
      }
      if (h > 0.f)
        pair_s[base + (int)__popcll(mask & ((1ull << lane) - 1ull))] =
            make_float2(h, __int_as_float(tid));
      const int cp = (cnt + 31) & ~31;
      if (tid < cp - cnt) pair_s[cnt + tid] = make_float2(0.f, __int_as_float(0));
      if (tid == 0) cntp_s = cp;
      if (tid < O_) {
        float o = myb;
#pragma unroll
        for (int w = 0; w < 8; ++w) o += wpart_s[w][tid];
        net_b[(size_t)(t + 1) * O_ + tid] = o;
      }
    }
    __syncthreads();
    cntp = cntp_s;
  }
}

extern "C" void kernel_launch(void* const* d_in, const int* in_sizes, int n_in,
                              void* d_out, int out_size, void* d_ws,
                              size_t ws_size, hipStream_t stream) {
  const float* x = (const float*)d_in[0];
  const float* noise = (const float*)d_in[1];
  const float* W_i2h = (const float*)d_in[2];
  const float* b_i2h = (const float*)d_in[3];
  const float* W_h2h = (const float*)d_in[4];
  const float* b_h2h = (const float*)d_in[5];
  const float* W_h2o = (const float*)d_in[6];
  const float* b_h2o = (const float*)d_in[7];
  const int* tau = (const int*)d_in[8];
  const int* dt = (const int*)d_in[9];

  float* out_net = (float*)d_out;
  float* out_rnn = (float*)d_out + (size_t)B_ * (T_ + 1) * O_;

  if (d_ws != nullptr && ws_size >= (size_t)WS_NEED) {
    unsigned* WTp = (unsigned*)d_ws;
    float* recs = (float*)((char*)d_ws + WT_BYTES);
    int* flags = (int*)((char*)d_ws + FLAGS_OFF);
    hipLaunchKernelGGL(pack_w, dim3(WT_WORDS / 256), dim3(256), 0, stream,
                       W_h2h, WTp);
    // zero flags every call (stream-ordered) -> no stale-flag race on replay
    hipMemsetAsync(flags, 0, B_ * NQ * sizeof(int), stream);
    hipLaunchKernelGGL(rnn4, dim3(B_ * NQ), dim3(1024), 0, stream, x, noise,
                       W_i2h, b_i2h, b_h2h, W_h2o, b_h2o, tau, dt, WTp, recs,
                       flags, out_net, out_rnn);
  } else {
    hipLaunchKernelGGL(rnn_fallback, dim3(B_), dim3(1024), 0, stream, x, noise,
                       W_i2h, b_i2h, W_h2h, b_h2h, W_h2o, b_h2o, tau, dt,
                       out_net, out_rnn);
  }
}

// Round 4
// 2720.370 us; speedup vs baseline: 2.3817x; 2.3817x over previous
//
#include <hip/hip_runtime.h>

#define B_ 64
#define T_ 1024
#define I_ 16
#define H_ 512
#define O_ 3
#define NIN_ 103
#define NEX_ 409

#define NQ 4    // j-slices = blocks per batch cluster
#define JS 128  // j per slice
#define NS 8    // k-slices inside a block
#define REC_F 136
#define WT_WORDS (NQ * JS * 256)          // 131072 packed bf16x2 words
#define WT_BYTES (WT_WORDS * 4)           // 524288
#define REC_BYTES (B_ * 2 * NQ * REC_F * 4)  // 278528
#define FLAGS_OFF (WT_BYTES + REC_BYTES)
#define WS_NEED (FLAGS_OFF + B_ * NQ * 4)

#define AL(p) __hip_atomic_load((p), __ATOMIC_RELAXED, __HIP_MEMORY_SCOPE_AGENT)
#define AS(p, v) \
  __hip_atomic_store((p), (v), __ATOMIC_RELAXED, __HIP_MEMORY_SCOPE_AGENT)

__device__ __forceinline__ unsigned short f2bf(float f) {
  unsigned u = __float_as_uint(f);
  return (unsigned short)((u + 0x7fffu + ((u >> 16) & 1u)) >> 16);
}

// Pack W_h2h rows into bf16x2 words: WTp[q][j][p] = bf16(W[q*128+j][2p]) | bf16(W[..][2p+1])<<16
__global__ __launch_bounds__(256) void pack_w(const float* __restrict__ W,
                                              unsigned* __restrict__ WTp) {
  const int w = blockIdx.x * 256 + threadIdx.x;  // 131072 total
  const int q = w >> 15, j = (w >> 8) & (JS - 1), p = w & 255;
  const int jg = q * JS + j;
  const float a = W[jg * H_ + 2 * p];
  const float b = W[jg * H_ + 2 * p + 1];
  WTp[w] = (unsigned)f2bf(a) | ((unsigned)f2bf(b) << 16);
}

// ---------------------------------------------------------------------------
// 4-block-per-batch cluster RNN. Block (b,q) owns output rows [q*128,..+128)
// of W_h2h, LDS-resident as bf16 pairs. Cross-block exchange: RELAXED
// agent-scope atomics only (they operate at the Infinity-Cache coherence
// point; acquire/release would emit per-step buffer_wbl2/buffer_inv L2
// maintenance -- the R3 6.6us/step bug). Ordering: producer = recs stores
// drained by __syncthreads' vmcnt(0) before flag store; consumer = in-order
// issue after the flag poll's dependent branch. Flags are zeroed by a
// stream-ordered memset each call; monotone >= waits + depth-2 parity recs.
// 256 blocks x 134KB LDS = 1 block/CU, all co-resident by construction.
// ---------------------------------------------------------------------------
__global__ __launch_bounds__(1024, 1) void rnn4(
    const float* __restrict__ x, const float* __restrict__ noise,
    const float* __restrict__ W_i2h, const float* __restrict__ b_i2h,
    const float* __restrict__ b_h2h, const float* __restrict__ W_h2o,
    const float* __restrict__ b_h2o, const int* __restrict__ taup,
    const int* __restrict__ dtp, const unsigned* __restrict__ WTp,
    float* __restrict__ recs, int* __restrict__ flags,
    float* __restrict__ out_net, float* __restrict__ out_rnn) {
  __shared__ unsigned wt_s[WT_WORDS / NQ];  // 128 KB, XOR-16B swizzled rows
  __align__(16) __shared__ float h_s[H_];
  __align__(16) __shared__ float partial_s[NS * JS];
  __shared__ float x_s[I_];
  __shared__ float tails_in[18];
  __shared__ float tail_own[2][2][3];

  const int tid = threadIdx.x;
  const int g = blockIdx.x;
  const int b = (g >> 5) * 8 + (g & 7);  // cluster's 4 blocks share g%8 (XCD)
  const int q = (g >> 3) & 3;
  const int lane = tid & 63;
  const int wave = tid >> 6;

  const float alpha = (float)dtp[0] / (float)taup[0];
  const float nzscale = (float)(sqrt(2.0 * (double)alpha) * 0.01);

  // ---- setup ----
  char* wt_c = (char*)wt_s;
  {
    const uint4* gsrc = (const uint4*)WTp + q * 8192;
    for (int idx = tid; idx < 8192; idx += 1024) {
      const int j = idx >> 6, cw = idx & 63;
      *(uint4*)(wt_c + j * 1024 + ((cw * 16) ^ ((j & 7) << 4))) = gsrc[idx];
    }
  }
  float wi[I_], cb = 0.f, w30 = 0.f, w31 = 0.f, w32 = 0.f, bo = 0.f;
  if (tid < JS) {
    const int jg = q * JS + tid;
#pragma unroll
    for (int i = 0; i < I_; ++i) wi[i] = W_i2h[jg * I_ + i];
    cb = b_i2h[jg] + b_h2h[jg];
    if (jg >= NIN_) {
      const int e = jg - NIN_;
      w30 = W_h2o[e];
      w31 = W_h2o[NEX_ + e];
      w32 = W_h2o[2 * NEX_ + e];
    }
  }
  if (tid >= JS && tid < JS + O_) bo = b_h2o[tid - JS];
  if (tid < H_) h_s[tid] = 0.f;
  if (tid < JS) out_rnn[(size_t)b * (T_ + 1) * H_ + q * JS + tid] = 0.f;
  if (q == 0 && tid >= JS && tid < JS + O_)
    out_net[(size_t)b * (T_ + 1) * O_ + (tid - JS)] = 0.f;
  __syncthreads();

  const int s = tid >> 7;       // k-slice 0..7
  const int j = tid & (JS - 1); // output within slice
  const int sw = (j & 7) << 4;
  const int rowbase = j * 1024;
  const int fb = b * NQ;

  for (int t = 0; t < T_; ++t) {
    // ---- prologue: hoisted loads, then per-peer spin + h staging ----
    float nz = 0.f, xv = 0.f;
    if (tid < JS) nz = noise[((size_t)b * T_ + t) * H_ + q * JS + tid];
    if (tid < I_) xv = x[((size_t)b * T_ + t) * I_ + tid];

    if (t > 0) {
      if (wave < 6) {  // waves 0-5: 2 waves per peer, poll + load 64 h each
        const int p3 = wave >> 1;
        const int qs = p3 + (p3 >= q ? 1 : 0);
        while (AL(&flags[fb + qs]) < t) __builtin_amdgcn_s_sleep(1);
        const int e = (wave & 1) * 64 + lane;
        const float* r = recs + ((size_t)(b * 2 + (t & 1)) * NQ + qs) * REC_F;
        h_s[qs * JS + e] = AL(r + e);
      } else if (wave == 6 && q == 0) {  // wave 6: tails from the 3 peers
        bool rdy;
        do {
          rdy = (lane < 3) ? (AL(&flags[fb + 1 + lane]) >= t) : true;
          if (!__all(rdy)) __builtin_amdgcn_s_sleep(1);
        } while (!__all(rdy));
        if (lane < 18) {
          const int r3 = lane / 6, c = lane % 6;
          const float* r =
              recs + ((size_t)(b * 2 + (t & 1)) * NQ + (r3 + 1)) * REC_F;
          tails_in[lane] = AL(r + JS + c);
        }
      }
    }
    if (tid < I_) x_s[tid] = xv;
    __syncthreads();  // A: h_s/x_s staged

    // ---- dense GEMV from LDS (bf16 W, fp32 h; h reads are wave-uniform
    //      broadcasts, w reads are swizzled b128) ----
    float acc = 0.f;
#pragma unroll
    for (int u = 0; u < 8; ++u) {
      const int off = s * 128 + u * 16;
      const uint4 w4 = *(const uint4*)(wt_c + rowbase + (off ^ sw));
      const float4 hA = *(const float4*)&h_s[s * 64 + u * 8];
      const float4 hB = *(const float4*)&h_s[s * 64 + u * 8 + 4];
      acc += __uint_as_float(w4.x << 16) * hA.x;
      acc += __uint_as_float(w4.x & 0xffff0000u) * hA.y;
      acc += __uint_as_float(w4.y << 16) * hA.z;
      acc += __uint_as_float(w4.y & 0xffff0000u) * hA.w;
      acc += __uint_as_float(w4.z << 16) * hB.x;
      acc += __uint_as_float(w4.z & 0xffff0000u) * hB.y;
      acc += __uint_as_float(w4.w << 16) * hB.z;
      acc += __uint_as_float(w4.w & 0xffff0000u) * hB.w;
    }
    partial_s[s * JS + j] = acc;
    __syncthreads();  // B: partials ready

    // ---- epilogue ----
    if (tid < JS) {
      const int jg = q * JS + tid;
      float sum = 0.f;
#pragma unroll
      for (int s2 = 0; s2 < NS; ++s2) sum += partial_s[s2 * JS + tid];
      float xi = 0.f;
#pragma unroll
      for (int i = 0; i < I_; ++i) xi += wi[i] * x_s[i];
      const float pre = alpha * (sum + xi + cb) + nzscale * nz;
      const float h = fmaxf(pre, 0.f);
      out_rnn[((size_t)b * (T_ + 1) + (t + 1)) * H_ + jg] = h;
      h_s[jg] = h;  // own slice for next GEMV
      float* r = recs + ((size_t)(b * 2 + ((t + 1) & 1)) * NQ + q) * REC_F;
      AS(r + tid, h);
      float p0 = (jg >= NIN_) ? h * w30 : 0.f;
      float p1 = (jg >= NIN_) ? h * w31 : 0.f;
      float p2 = (jg >= NIN_) ? h * w32 : 0.f;
#pragma unroll
      for (int off = 32; off >= 1; off >>= 1) {
        p0 += __shfl_xor(p0, off, 64);
        p1 += __shfl_xor(p1, off, 64);
        p2 += __shfl_xor(p2, off, 64);
      }
      const int wv = tid >> 6;
      if ((tid & 63) == 0) {
        AS(r + JS + wv * 3 + 0, p0);
        AS(r + JS + wv * 3 + 1, p1);
        AS(r + JS + wv * 3 + 2, p2);
        tail_own[(t + 1) & 1][wv][0] = p0;
        tail_own[(t + 1) & 1][wv][1] = p1;
        tail_own[(t + 1) & 1][wv][2] = p2;
      }
    }
    if (q == 0 && t > 0 && tid >= JS && tid < JS + O_) {
      const int o = tid - JS;
      float v = bo;
#pragma unroll
      for (int r3 = 0; r3 < 3; ++r3)
#pragma unroll
        for (int w = 0; w < 2; ++w) v += tails_in[r3 * 6 + w * 3 + o];
      v += tail_own[t & 1][0][o] + tail_own[t & 1][1][o];
      out_net[((size_t)b * (T_ + 1) + t) * O_ + o] = v;
    }
    __syncthreads();  // C: all stores drained (vmcnt0) before flag post
    if (tid == 0) AS(&flags[fb + q], t + 1);
  }

  // final out_net[b][T] from records(T) (parity T&1 == 0)
  if (q == 0) {
    if (tid < NQ) {
      while (AL(&flags[fb + tid]) < T_) __builtin_amdgcn_s_sleep(1);
    }
    __syncthreads();
    if (tid >= 384 && tid < 402) {
      const int i = tid - 384, r3 = i / 6, c = i % 6;
      const float* r = recs + ((size_t)(b * 2 + 0) * NQ + (r3 + 1)) * REC_F;
      tails_in[i] = AL(r + JS + c);
    }
    __syncthreads();
    if (tid >= JS && tid < JS + O_) {
      const int o = tid - JS;
      float v = bo;
#pragma unroll
      for (int r3 = 0; r3 < 3; ++r3)
#pragma unroll
        for (int w = 0; w < 2; ++w) v += tails_in[r3 * 6 + w * 3 + o];
      v += tail_own[0][0][o] + tail_own[0][1][o];
      out_net[((size_t)b * (T_ + 1) + T_) * O_ + o] = v;
    }
  }
}

// ---------------------------------------------------------------------------
// Fallback (ws too small): single-block-per-batch kernel with sparse
// outer-product from strided W. Slow but correct, needs no workspace.
// ---------------------------------------------------------------------------
__global__ __launch_bounds__(1024, 1) void rnn_fallback(
    const float* __restrict__ x, const float* __restrict__ noise,
    const float* __restrict__ W_i2h, const float* __restrict__ b_i2h,
    const float* __restrict__ Wh, const float* __restrict__ b_h2h,
    const float* __restrict__ W_h2o, const float* __restrict__ b_h2o,
    const int* __restrict__ taup, const int* __restrict__ dtp,
    float* __restrict__ out_net, float* __restrict__ out_rnn) {
  __shared__ float2 pair_s[544];
  __shared__ float cb_s[H_];
  __shared__ float w3_s[3 * 416];
  __shared__ float wpart_s[8][3];
  __shared__ int wcnt_s[8];
  __shared__ float x_s[I_];
  __shared__ int cntp_s;
  __align__(16) __shared__ float partial_s[8 * H_];

  const int tid = threadIdx.x;
  const int b = blockIdx.x;
  const int lane = tid & 63;
  const int wave = tid >> 6;
  const int slice = tid >> 7;
  const int j4 = (tid & 127) * 4;

  const float alpha = (float)dtp[0] / (float)taup[0];
  const float nzscale = (float)(sqrt(2.0 * (double)alpha) * 0.01);

  float wi[I_];
  if (tid < H_) {
#pragma unroll
    for (int i = 0; i < I_; ++i) wi[i] = W_i2h[tid * I_ + i];
    cb_s[tid] = b_i2h[tid] + b_h2h[tid];
  }
  for (int idx = tid; idx < O_ * NEX_; idx += 1024) {
    int o = idx / NEX_, e = idx - o * NEX_;
    w3_s[o * 416 + e] = W_h2o[idx];
  }
  const float myb = (tid < O_) ? b_h2o[tid] : 0.f;
  if (tid == 0) cntp_s = 0;
  float* rnn_b = out_rnn + (size_t)b * (T_ + 1) * H_;
  float* net_b = out_net + (size_t)b * (T_ + 1) * O_;
  if (tid < H_) rnn_b[tid] = 0.f;
  if (tid < O_) net_b[tid] = 0.f;
  __syncthreads();

  int cntp = 0;
  for (int t = 0; t < T_; ++t) {
    float nzv = 0.f, xv = 0.f;
    if (tid < H_) nzv = noise[((size_t)b * T_ + t) * H_ + tid];
    if (tid < I_) xv = x[((size_t)b * T_ + t) * I_ + tid];
    float4 acc = {0.f, 0.f, 0.f, 0.f};
    const int iters = cntp >> 3;
    for (int r = 0; r < iters; r += 4) {
#pragma unroll
      for (int u = 0; u < 4; ++u) {
        const float2 p = pair_s[(r + u) * 8 + slice];
        const int k = __float_as_int(p.y);
        acc.x += p.x * Wh[(size_t)(j4 + 0) * H_ + k];
        acc.y += p.x * Wh[(size_t)(j4 + 1) * H_ + k];
        acc.z += p.x * Wh[(size_t)(j4 + 2) * H_ + k];
        acc.w += p.x * Wh[(size_t)(j4 + 3) * H_ + k];
      }
    }
    if (tid < I_) x_s[tid] = xv;
    *reinterpret_cast<float4*>(partial_s + slice * H_ + j4) = acc;
    __syncthreads();
    unsigned long long mask = 0ull;
    float h = 0.f;
    if (tid < H_) {
      float sum = 0.f;
#pragma unroll
      for (int s2 = 0; s2 < 8; ++s2) sum += partial_s[s2 * H_ + tid];
      float xi = 0.f;
#pragma unroll
      for (int i = 0; i < I_; ++i) xi += wi[i] * x_s[i];
      const float pre = alpha * (sum + xi + cb_s[tid]) + nzscale * nzv;
      h = fmaxf(pre, 0.f);
      rnn_b[(size_t)(t + 1) * H_ + tid] = h;
      float p0 = 0.f, p1 = 0.f, p2 = 0.f;
      if (tid >= NIN_) {
        const int e = tid - NIN_;
        p0 = h * w3_s[e];
        p1 = h * w3_s[416 + e];
        p2 = h * w3_s[832 + e];
      }
#pragma unroll
      for (int off = 32; off >= 1; off >>= 1) {
        p0 += __shfl_xor(p0, off, 64);
        p1 += __shfl_xor(p1, off, 64);
        p2 += __shfl_xor(p2, off, 64);
      }
      mask = __ballot(h > 0.f);
      if (lane == 0) {
        wcnt_s[wave] = (int)__popcll(mask);
        wpart_s[wave][0] = p0;
        wpart_s[wave][1] = p1;
        wpart_s[wave][2] = p2;
      }
    }
    __syncthreads();
    if (tid < H_) {
      int base = 0, cnt = 0;
#pragma unroll
      for (int w = 0; w < 8; ++w) {
        const int c = wcnt_s[w];
        if (w < wave) base += c;
        cnt += c;
      }
      if (h > 0.f)
        pair_s[base + (int)__popcll(mask & ((1ull << lane) - 1ull))] =
            make_float2(h, __int_as_float(tid));
      const int cp = (cnt + 31) & ~31;
      if (tid < cp - cnt) pair_s[cnt + tid] = make_float2(0.f, __int_as_float(0));
      if (tid == 0) cntp_s = cp;
      if (tid < O_) {
        float o = myb;
#pragma unroll
        for (int w = 0; w < 8; ++w) o += wpart_s[w][tid];
        net_b[(size_t)(t + 1) * O_ + tid] = o;
      }
    }
    __syncthreads();
    cntp = cntp_s;
  }
}

extern "C" void kernel_launch(void* const* d_in, const int* in_sizes, int n_in,
                              void* d_out, int out_size, void* d_ws,
                              size_t ws_size, hipStream_t stream) {
  const float* x = (const float*)d_in[0];
  const float* noise = (const float*)d_in[1];
  const float* W_i2h = (const float*)d_in[2];
  const float* b_i2h = (const float*)d_in[3];
  const float* W_h2h = (const float*)d_in[4];
  const float* b_h2h = (const float*)d_in[5];
  const float* W_h2o = (const float*)d_in[6];
  const float* b_h2o = (const float*)d_in[7];
  const int* tau = (const int*)d_in[8];
  const int* dt = (const int*)d_in[9];

  float* out_net = (float*)d_out;
  float* out_rnn = (float*)d_out + (size_t)B_ * (T_ + 1) * O_;

  if (d_ws != nullptr && ws_size >= (size_t)WS_NEED) {
    unsigned* WTp = (unsigned*)d_ws;
    float* recs = (float*)((char*)d_ws + WT_BYTES);
    int* flags = (int*)((char*)d_ws + FLAGS_OFF);
    hipLaunchKernelGGL(pack_w, dim3(WT_WORDS / 256), dim3(256), 0, stream,
                       W_h2h, WTp);
    // zero flags every call (stream-ordered) -> no stale-flag race on replay
    hipMemsetAsync(flags, 0, B_ * NQ * sizeof(int), stream);
    hipLaunchKernelGGL(rnn4, dim3(B_ * NQ), dim3(1024), 0, stream, x, noise,
                       W_i2h, b_i2h, b_h2h, W_h2o, b_h2o, tau, dt, WTp, recs,
                       flags, out_net, out_rnn);
  } else {
    hipLaunchKernelGGL(rnn_fallback, dim3(B_), dim3(1024), 0, stream, x, noise,
                       W_i2h, b_i2h, W_h2h, b_h2h, W_h2o, b_h2o, tau, dt,
                       out_net, out_rnn);
  }
}